// Round 11
// baseline (149.459 us; speedup 1.0000x reference)
//
#include <hip/hip_runtime.h>

#define NN 262144   // nodes
#define DD 256      // channels
#define BB 1024     // graphs
#define GEPS 1e-5f
#define GPB 4               // graphs per block (pipelined)
#define NBLK (BB / GPB)     // 256 blocks -> 1 per CU (16 waves, VGPR<=128)
#define NCHUNK 16           // 16 chunks x 16 rows = 256 rows register capacity

typedef float floatx4 __attribute__((ext_vector_type(4)));

// R11: register-resident segments (R10) + read/write DUPLEX via pipelining.
// 256 blocks, 4 consecutive graphs each. After graph g's stats, one unrolled
// loop stores graph g (from registers, NT) while loading graph g+1 into the
// same registers -> the CU issues reads and writes concurrently for 3/4 of
// the runtime, instead of R10's strict read-phase/write-phase alternation
// (per-CU single-direction cap ~16-20 GB/s was the ~130 us wall).
__global__ __launch_bounds__(1024) void k_main(const float4* __restrict__ x,
                                               const int* __restrict__ batch,
                                               const float4* __restrict__ w,
                                               const float4* __restrict__ bi,
                                               float4* __restrict__ out) {
    __shared__ int   s_coarse[GPB + 1];
    __shared__ int   s_bound[GPB + 1];
    __shared__ float red_s[16];
    __shared__ float red_q[16];
    __shared__ float bc[2];

    const int g0   = blockIdx.x * GPB;
    const int tid  = threadIdx.x;
    const int wid  = tid >> 6;     // 0..15
    const int lane = tid & 63;

    // ---- 5 boundaries: lower_bound(batch, g0+k), k=0..4 ----
    if (tid <= GPB) s_coarse[tid] = NN;
    __syncthreads();
    {
        const int idx = tid << 8;              // 1024 probes, stride 256
        const int v   = batch[idx];
        const int pv  = __shfl_up(v, 1, 64);   // prev probe (lane0: own v)
        #pragma unroll
        for (int k = 0; k <= GPB; ++k) {
            const int tgt = g0 + k;
            // only boundary-adjacent probes (and wave lane0) hit the atomic
            if (v >= tgt && (lane == 0 || pv < tgt))
                atomicMin(&s_coarse[k], idx);
        }
    }
    __syncthreads();
    {
        const int sub = tid >> 8;              // 0..3
        const int t   = tid & 255;
        for (int k = sub; k <= GPB; k += 4) {
            const int tgt = g0 + k;
            const int cc  = s_coarse[k];
            const int i   = cc - 255 + t;      // window covers cc-255 .. cc
            if (i >= 0) {
                const int vi  = (i < NN) ? batch[i] : 0x7fffffff;
                const int vim = (i > 0) ? batch[i - 1] : (-2147483647 - 1);
                if (vi >= tgt && vim < tgt) s_bound[k] = i;   // unique hit
            }
        }
    }
    __syncthreads();

    const float4 wv = w[lane];
    const float4 bv = bi[lane];

    float4 v[NCHUNK];
    float  s = 0.0f, q = 0.0f;
    int sA = s_bound[0], eA = s_bound[1];

    // ---- prologue: load graph 0 into registers, accumulate ----
    #pragma unroll
    for (int i = 0; i < NCHUNK; ++i) {
        const int r = sA + wid + i * 16;       // wave-uniform guard
        if (r < eA) {
            float4 t4 = x[r * 64 + lane];
            s += t4.x + t4.y + t4.z + t4.w;
            q += t4.x * t4.x + t4.y * t4.y + t4.z * t4.z + t4.w * t4.w;
            asm volatile("" : "+v"(t4.x), "+v"(t4.y), "+v"(t4.z), "+v"(t4.w));
            v[i] = t4;
        }
    }
    for (int r = sA + wid + NCHUNK * 16; r < eA; r += 16) {   // overflow acc
        const float4 t4 = x[r * 64 + lane];
        s += t4.x + t4.y + t4.z + t4.w;
        q += t4.x * t4.x + t4.y * t4.y + t4.z * t4.z + t4.w * t4.w;
    }

    #pragma unroll
    for (int g = 0; g < GPB; ++g) {
        // ---- stats for graph g from (s,q) ----
        float rs = s, rq = q;
        #pragma unroll
        for (int off = 32; off; off >>= 1) {
            rs += __shfl_down(rs, off, 64);
            rq += __shfl_down(rq, off, 64);
        }
        if (lane == 0) { red_s[wid] = rs; red_q[wid] = rq; }
        __syncthreads();
        if (tid == 0) {
            float ts = 0.0f, tq = 0.0f;
            #pragma unroll
            for (int i = 0; i < 16; ++i) { ts += red_s[i]; tq += red_q[i]; }
            const float norm = fmaxf((float)(eA - sA), 1.0f) * (float)DD;
            const float mean = ts / norm;
            const float var  = fmaxf(tq / norm - mean * mean, 0.0f);
            bc[0] = mean;
            bc[1] = 1.0f / (sqrtf(var) + GEPS);
        }
        __syncthreads();
        const float mean = bc[0];
        const float inv  = bc[1];
        __syncthreads();                       // bc/red reusable next iter

        const bool haveNext = (g + 1 < GPB);
        const int  sB = haveNext ? s_bound[g + 1] : 0;
        const int  eB = haveNext ? s_bound[g + 2] : 0;
        s = 0.0f; q = 0.0f;

        // ---- duplex loop: store graph g from regs, load graph g+1 ----
        #pragma unroll
        for (int i = 0; i < NCHUNK; ++i) {
            const int ro = sA + wid + i * 16;
            if (ro < eA) {
                floatx4 o;
                o.x = (v[i].x - mean) * inv * wv.x + bv.x;
                o.y = (v[i].y - mean) * inv * wv.y + bv.y;
                o.z = (v[i].z - mean) * inv * wv.z + bv.z;
                o.w = (v[i].w - mean) * inv * wv.w + bv.w;
                __builtin_nontemporal_store(o, (floatx4*)&out[ro * 64 + lane]);
            }
            if (haveNext) {
                const int ri = sB + wid + i * 16;
                if (ri < eB) {
                    float4 t4 = x[ri * 64 + lane];
                    s += t4.x + t4.y + t4.z + t4.w;
                    q += t4.x * t4.x + t4.y * t4.y + t4.z * t4.z + t4.w * t4.w;
                    asm volatile("" : "+v"(t4.x), "+v"(t4.y), "+v"(t4.z), "+v"(t4.w));
                    v[i] = t4;
                }
            }
        }
        // overflow-out for graph g (rows >256: L3-hot re-read)
        for (int r = sA + wid + NCHUNK * 16; r < eA; r += 16) {
            const float4 t4 = x[r * 64 + lane];
            floatx4 o;
            o.x = (t4.x - mean) * inv * wv.x + bv.x;
            o.y = (t4.y - mean) * inv * wv.y + bv.y;
            o.z = (t4.z - mean) * inv * wv.z + bv.z;
            o.w = (t4.w - mean) * inv * wv.w + bv.w;
            __builtin_nontemporal_store(o, (floatx4*)&out[r * 64 + lane]);
        }
        // overflow-in for graph g+1 (accumulate only)
        if (haveNext) {
            for (int r = sB + wid + NCHUNK * 16; r < eB; r += 16) {
                const float4 t4 = x[r * 64 + lane];
                s += t4.x + t4.y + t4.z + t4.w;
                q += t4.x * t4.x + t4.y * t4.y + t4.z * t4.z + t4.w * t4.w;
            }
        }
        sA = sB; eA = eB;
    }
}

extern "C" void kernel_launch(void* const* d_in, const int* in_sizes, int n_in,
                              void* d_out, int out_size, void* d_ws, size_t ws_size,
                              hipStream_t stream) {
    const float4* x     = (const float4*)d_in[0];
    const int*    batch = (const int*)d_in[1];
    const float4* w     = (const float4*)d_in[2];
    const float4* bi    = (const float4*)d_in[3];
    float4*       out   = (float4*)d_out;

    k_main<<<NBLK, 1024, 0, stream>>>(x, batch, w, bi, out);
}

// Round 12
// 148.901 us; speedup vs baseline: 1.0037x; 1.0037x over previous
//
#include <hip/hip_runtime.h>

#define NN 262144   // nodes
#define DD 256      // channels
#define BB 1024     // graphs
#define GEPS 1e-5f
#define GPB 4               // graphs per block (pipelined)
#define NBLK (BB / GPB)     // 256 blocks -> 1 per CU (16 waves)
#define NCHUNK 16           // 16 chunks x 16 rows = 256 rows register capacity

typedef float floatx4 __attribute__((ext_vector_type(4)));

// R12 = R11 with ONE change: __launch_bounds__(1024, 4). R11's counters
// showed VGPR=64 + WRITE 385MB: the compiler targeted 2 blocks/CU (64-VGPR
// cap) and spilled v[16] to scratch -- the pipelined registers round-tripped
// through memory. 4 waves/EU min = 1 block/CU = 128-VGPR cap, which fits the
// duplex loop's ~110 live VGPRs without spill.
__global__ __launch_bounds__(1024, 4) void k_main(const float4* __restrict__ x,
                                                  const int* __restrict__ batch,
                                                  const float4* __restrict__ w,
                                                  const float4* __restrict__ bi,
                                                  float4* __restrict__ out) {
    __shared__ int   s_coarse[GPB + 1];
    __shared__ int   s_bound[GPB + 1];
    __shared__ float red_s[16];
    __shared__ float red_q[16];
    __shared__ float bc[2];

    const int g0   = blockIdx.x * GPB;
    const int tid  = threadIdx.x;
    const int wid  = tid >> 6;     // 0..15
    const int lane = tid & 63;

    // ---- 5 boundaries: lower_bound(batch, g0+k), k=0..4 ----
    if (tid <= GPB) s_coarse[tid] = NN;
    __syncthreads();
    {
        const int idx = tid << 8;              // 1024 probes, stride 256
        const int v   = batch[idx];
        const int pv  = __shfl_up(v, 1, 64);   // prev probe (lane0: own v)
        #pragma unroll
        for (int k = 0; k <= GPB; ++k) {
            const int tgt = g0 + k;
            if (v >= tgt && (lane == 0 || pv < tgt))
                atomicMin(&s_coarse[k], idx);
        }
    }
    __syncthreads();
    {
        const int sub = tid >> 8;              // 0..3
        const int t   = tid & 255;
        for (int k = sub; k <= GPB; k += 4) {
            const int tgt = g0 + k;
            const int cc  = s_coarse[k];
            const int i   = cc - 255 + t;      // window covers cc-255 .. cc
            if (i >= 0) {
                const int vi  = (i < NN) ? batch[i] : 0x7fffffff;
                const int vim = (i > 0) ? batch[i - 1] : (-2147483647 - 1);
                if (vi >= tgt && vim < tgt) s_bound[k] = i;   // unique hit
            }
        }
    }
    __syncthreads();

    const float4 wv = w[lane];
    const float4 bv = bi[lane];

    float4 v[NCHUNK];
    float  s = 0.0f, q = 0.0f;
    int sA = s_bound[0], eA = s_bound[1];

    // ---- prologue: load graph 0 into registers, accumulate ----
    #pragma unroll
    for (int i = 0; i < NCHUNK; ++i) {
        const int r = sA + wid + i * 16;       // wave-uniform guard
        if (r < eA) {
            float4 t4 = x[r * 64 + lane];
            s += t4.x + t4.y + t4.z + t4.w;
            q += t4.x * t4.x + t4.y * t4.y + t4.z * t4.z + t4.w * t4.w;
            asm volatile("" : "+v"(t4.x), "+v"(t4.y), "+v"(t4.z), "+v"(t4.w));
            v[i] = t4;
        }
    }
    for (int r = sA + wid + NCHUNK * 16; r < eA; r += 16) {   // overflow acc
        const float4 t4 = x[r * 64 + lane];
        s += t4.x + t4.y + t4.z + t4.w;
        q += t4.x * t4.x + t4.y * t4.y + t4.z * t4.z + t4.w * t4.w;
    }

    #pragma unroll
    for (int g = 0; g < GPB; ++g) {
        // ---- stats for graph g from (s,q) ----
        float rs = s, rq = q;
        #pragma unroll
        for (int off = 32; off; off >>= 1) {
            rs += __shfl_down(rs, off, 64);
            rq += __shfl_down(rq, off, 64);
        }
        if (lane == 0) { red_s[wid] = rs; red_q[wid] = rq; }
        __syncthreads();
        if (tid == 0) {
            float ts = 0.0f, tq = 0.0f;
            #pragma unroll
            for (int i = 0; i < 16; ++i) { ts += red_s[i]; tq += red_q[i]; }
            const float norm = fmaxf((float)(eA - sA), 1.0f) * (float)DD;
            const float mean = ts / norm;
            const float var  = fmaxf(tq / norm - mean * mean, 0.0f);
            bc[0] = mean;
            bc[1] = 1.0f / (sqrtf(var) + GEPS);
        }
        __syncthreads();
        const float mean = bc[0];
        const float inv  = bc[1];
        __syncthreads();                       // bc/red reusable next iter

        const bool haveNext = (g + 1 < GPB);
        const int  sB = haveNext ? s_bound[g + 1] : 0;
        const int  eB = haveNext ? s_bound[g + 2] : 0;
        s = 0.0f; q = 0.0f;

        // ---- duplex loop: store graph g from regs, load graph g+1 ----
        #pragma unroll
        for (int i = 0; i < NCHUNK; ++i) {
            const int ro = sA + wid + i * 16;
            if (ro < eA) {
                floatx4 o;
                o.x = (v[i].x - mean) * inv * wv.x + bv.x;
                o.y = (v[i].y - mean) * inv * wv.y + bv.y;
                o.z = (v[i].z - mean) * inv * wv.z + bv.z;
                o.w = (v[i].w - mean) * inv * wv.w + bv.w;
                __builtin_nontemporal_store(o, (floatx4*)&out[ro * 64 + lane]);
            }
            if (haveNext) {
                const int ri = sB + wid + i * 16;
                if (ri < eB) {
                    float4 t4 = x[ri * 64 + lane];
                    s += t4.x + t4.y + t4.z + t4.w;
                    q += t4.x * t4.x + t4.y * t4.y + t4.z * t4.z + t4.w * t4.w;
                    asm volatile("" : "+v"(t4.x), "+v"(t4.y), "+v"(t4.z), "+v"(t4.w));
                    v[i] = t4;
                }
            }
        }
        // overflow-out for graph g (rows >256: L3-hot re-read)
        for (int r = sA + wid + NCHUNK * 16; r < eA; r += 16) {
            const float4 t4 = x[r * 64 + lane];
            floatx4 o;
            o.x = (t4.x - mean) * inv * wv.x + bv.x;
            o.y = (t4.y - mean) * inv * wv.y + bv.y;
            o.z = (t4.z - mean) * inv * wv.z + bv.z;
            o.w = (t4.w - mean) * inv * wv.w + bv.w;
            __builtin_nontemporal_store(o, (floatx4*)&out[r * 64 + lane]);
        }
        // overflow-in for graph g+1 (accumulate only)
        if (haveNext) {
            for (int r = sB + wid + NCHUNK * 16; r < eB; r += 16) {
                const float4 t4 = x[r * 64 + lane];
                s += t4.x + t4.y + t4.z + t4.w;
                q += t4.x * t4.x + t4.y * t4.y + t4.z * t4.z + t4.w * t4.w;
            }
        }
        sA = sB; eA = eB;
    }
}

extern "C" void kernel_launch(void* const* d_in, const int* in_sizes, int n_in,
                              void* d_out, int out_size, void* d_ws, size_t ws_size,
                              hipStream_t stream) {
    const float4* x     = (const float4*)d_in[0];
    const int*    batch = (const int*)d_in[1];
    const float4* w     = (const float4*)d_in[2];
    const float4* bi    = (const float4*)d_in[3];
    float4*       out   = (float4*)d_out;

    k_main<<<NBLK, 1024, 0, stream>>>(x, batch, w, bi, out);
}

// Round 13
// 148.035 us; speedup vs baseline: 1.0096x; 1.0058x over previous
//
#include <hip/hip_runtime.h>

#define NN 262144   // nodes
#define DD 256      // channels
#define BB 1024     // graphs
#define GEPS 1e-5f
#define GPB 4               // graphs per block (pipelined)
#define NBLK (BB / GPB)     // 256 blocks -> 1 per CU (16 waves)
#define NCHUNK 16           // 16 chunks x 16 rows = 256 rows register capacity

typedef float floatx4 __attribute__((ext_vector_type(4)));

// R13 = R12 with ONE change: amdgpu_waves_per_eu(4,4). R12 kept VGPR=64 +
// 123MB scratch despite __launch_bounds__(1024,4): that arg only bounds the
// minimum waves/EU; the allocator still TARGETED 8 waves/EU and clamped to
// 64 VGPRs. waves_per_eu(4,4) pins occupancy at exactly 4 waves/EU
// (1 block/CU), so the allocator has 128 VGPRs and no reason to spill the
// 64-VGPR v[] array.
__global__ __launch_bounds__(1024)
__attribute__((amdgpu_waves_per_eu(4, 4)))
void k_main(const float4* __restrict__ x,
            const int* __restrict__ batch,
            const float4* __restrict__ w,
            const float4* __restrict__ bi,
            float4* __restrict__ out) {
    __shared__ int   s_coarse[GPB + 1];
    __shared__ int   s_bound[GPB + 1];
    __shared__ float red_s[16];
    __shared__ float red_q[16];
    __shared__ float bc[2];

    const int g0   = blockIdx.x * GPB;
    const int tid  = threadIdx.x;
    const int wid  = tid >> 6;     // 0..15
    const int lane = tid & 63;

    // ---- 5 boundaries: lower_bound(batch, g0+k), k=0..4 ----
    if (tid <= GPB) s_coarse[tid] = NN;
    __syncthreads();
    {
        const int idx = tid << 8;              // 1024 probes, stride 256
        const int v   = batch[idx];
        const int pv  = __shfl_up(v, 1, 64);   // prev probe (lane0: own v)
        #pragma unroll
        for (int k = 0; k <= GPB; ++k) {
            const int tgt = g0 + k;
            if (v >= tgt && (lane == 0 || pv < tgt))
                atomicMin(&s_coarse[k], idx);
        }
    }
    __syncthreads();
    {
        const int sub = tid >> 8;              // 0..3
        const int t   = tid & 255;
        for (int k = sub; k <= GPB; k += 4) {
            const int tgt = g0 + k;
            const int cc  = s_coarse[k];
            const int i   = cc - 255 + t;      // window covers cc-255 .. cc
            if (i >= 0) {
                const int vi  = (i < NN) ? batch[i] : 0x7fffffff;
                const int vim = (i > 0) ? batch[i - 1] : (-2147483647 - 1);
                if (vi >= tgt && vim < tgt) s_bound[k] = i;   // unique hit
            }
        }
    }
    __syncthreads();

    const float4 wv = w[lane];
    const float4 bv = bi[lane];

    float4 v[NCHUNK];
    float  s = 0.0f, q = 0.0f;
    int sA = s_bound[0], eA = s_bound[1];

    // ---- prologue: load graph 0 into registers, accumulate ----
    #pragma unroll
    for (int i = 0; i < NCHUNK; ++i) {
        const int r = sA + wid + i * 16;       // wave-uniform guard
        if (r < eA) {
            float4 t4 = x[r * 64 + lane];
            s += t4.x + t4.y + t4.z + t4.w;
            q += t4.x * t4.x + t4.y * t4.y + t4.z * t4.z + t4.w * t4.w;
            asm volatile("" : "+v"(t4.x), "+v"(t4.y), "+v"(t4.z), "+v"(t4.w));
            v[i] = t4;
        }
    }
    for (int r = sA + wid + NCHUNK * 16; r < eA; r += 16) {   // overflow acc
        const float4 t4 = x[r * 64 + lane];
        s += t4.x + t4.y + t4.z + t4.w;
        q += t4.x * t4.x + t4.y * t4.y + t4.z * t4.z + t4.w * t4.w;
    }

    #pragma unroll
    for (int g = 0; g < GPB; ++g) {
        // ---- stats for graph g from (s,q) ----
        float rs = s, rq = q;
        #pragma unroll
        for (int off = 32; off; off >>= 1) {
            rs += __shfl_down(rs, off, 64);
            rq += __shfl_down(rq, off, 64);
        }
        if (lane == 0) { red_s[wid] = rs; red_q[wid] = rq; }
        __syncthreads();
        if (tid == 0) {
            float ts = 0.0f, tq = 0.0f;
            #pragma unroll
            for (int i = 0; i < 16; ++i) { ts += red_s[i]; tq += red_q[i]; }
            const float norm = fmaxf((float)(eA - sA), 1.0f) * (float)DD;
            const float mean = ts / norm;
            const float var  = fmaxf(tq / norm - mean * mean, 0.0f);
            bc[0] = mean;
            bc[1] = 1.0f / (sqrtf(var) + GEPS);
        }
        __syncthreads();
        const float mean = bc[0];
        const float inv  = bc[1];
        __syncthreads();                       // bc/red reusable next iter

        const bool haveNext = (g + 1 < GPB);
        const int  sB = haveNext ? s_bound[g + 1] : 0;
        const int  eB = haveNext ? s_bound[g + 2] : 0;
        s = 0.0f; q = 0.0f;

        // ---- duplex loop: store graph g from regs, load graph g+1 ----
        #pragma unroll
        for (int i = 0; i < NCHUNK; ++i) {
            const int ro = sA + wid + i * 16;
            if (ro < eA) {
                floatx4 o;
                o.x = (v[i].x - mean) * inv * wv.x + bv.x;
                o.y = (v[i].y - mean) * inv * wv.y + bv.y;
                o.z = (v[i].z - mean) * inv * wv.z + bv.z;
                o.w = (v[i].w - mean) * inv * wv.w + bv.w;
                __builtin_nontemporal_store(o, (floatx4*)&out[ro * 64 + lane]);
            }
            if (haveNext) {
                const int ri = sB + wid + i * 16;
                if (ri < eB) {
                    float4 t4 = x[ri * 64 + lane];
                    s += t4.x + t4.y + t4.z + t4.w;
                    q += t4.x * t4.x + t4.y * t4.y + t4.z * t4.z + t4.w * t4.w;
                    asm volatile("" : "+v"(t4.x), "+v"(t4.y), "+v"(t4.z), "+v"(t4.w));
                    v[i] = t4;
                }
            }
        }
        // overflow-out for graph g (rows >256: L3-hot re-read)
        for (int r = sA + wid + NCHUNK * 16; r < eA; r += 16) {
            const float4 t4 = x[r * 64 + lane];
            floatx4 o;
            o.x = (t4.x - mean) * inv * wv.x + bv.x;
            o.y = (t4.y - mean) * inv * wv.y + bv.y;
            o.z = (t4.z - mean) * inv * wv.z + bv.z;
            o.w = (t4.w - mean) * inv * wv.w + bv.w;
            __builtin_nontemporal_store(o, (floatx4*)&out[r * 64 + lane]);
        }
        // overflow-in for graph g+1 (accumulate only)
        if (haveNext) {
            for (int r = sB + wid + NCHUNK * 16; r < eB; r += 16) {
                const float4 t4 = x[r * 64 + lane];
                s += t4.x + t4.y + t4.z + t4.w;
                q += t4.x * t4.x + t4.y * t4.y + t4.z * t4.z + t4.w * t4.w;
            }
        }
        sA = sB; eA = eB;
    }
}

extern "C" void kernel_launch(void* const* d_in, const int* in_sizes, int n_in,
                              void* d_out, int out_size, void* d_ws, size_t ws_size,
                              hipStream_t stream) {
    const float4* x     = (const float4*)d_in[0];
    const int*    batch = (const int*)d_in[1];
    const float4* w     = (const float4*)d_in[2];
    const float4* bi    = (const float4*)d_in[3];
    float4*       out   = (float4*)d_out;

    k_main<<<NBLK, 1024, 0, stream>>>(x, batch, w, bi, out);
}